// Round 8
// baseline (254.491 us; speedup 1.0000x reference)
//
#include <hip/hip_runtime.h>
#include <hip/hip_bf16.h>

#define DIN 1024
#define NH 16
#define HD 64
#define SEQ 2048
#define NB 2

typedef __attribute__((ext_vector_type(8))) short bf16x8;
typedef __attribute__((ext_vector_type(4))) float f32x4;
typedef __attribute__((ext_vector_type(16))) float f32x16;
typedef __attribute__((ext_vector_type(4))) unsigned u32x4;

__device__ inline short f2bf(float f) {
  union { float f; unsigned u; } v; v.f = f;
  unsigned r = v.u + 0x7fff + ((v.u >> 16) & 1);
  return (short)(r >> 16);
}

// 2x f32 -> packed bf16 pair (lo, hi) in one instruction (T12 recipe)
__device__ inline unsigned pk2(float lo, float hi) {
  unsigned r;
  asm("v_cvt_pk_bf16_f32 %0, %1, %2" : "=v"(r) : "v"(lo), "v"(hi));
  return r;
}

// swap a.hi32lanes <-> b.lo32lanes in-place (both outputs usable)
__device__ inline void pl32swap(unsigned& a, unsigned& b) {
  asm("v_permlane32_swap_b32 %0, %1" : "+v"(a), "+v"(b));
}

union U8 { unsigned u[4]; bf16x8 v; };
__device__ inline bf16x8 mkfrag(unsigned a, unsigned b, unsigned c, unsigned d) {
  U8 x; x.u[0] = a; x.u[1] = b; x.u[2] = c; x.u[3] = d; return x.v;
}

__device__ __forceinline__ void gload_lds16(const void* g, void* l) {
  __builtin_amdgcn_global_load_lds(
      (const __attribute__((address_space(1))) unsigned*)g,
      (__attribute__((address_space(3))) unsigned*)l, 16, 0, 0);
}

// Wq/Wk/Wv [H][1024][64] fp32 -> Wt [3][H][64][1024] bf16 (transposed per head)
__global__ __launch_bounds__(256) void wt3_kernel(
    const float* __restrict__ Wq, const float* __restrict__ Wk, const float* __restrict__ Wv,
    short* __restrict__ out) {
  int zz = blockIdx.z; int which = zz >> 4, h = zz & 15;
  const float* in = (which == 0 ? Wq : (which == 1 ? Wk : Wv)) + (size_t)h * (DIN * HD);
  short* o = out + (size_t)which * (NH * HD * DIN) + (size_t)h * (HD * DIN);
  __shared__ float tile[64][65];
  int r0 = blockIdx.y * 64;
  int t = threadIdx.x;
  int r = t >> 2, cc = (t & 3) * 16;
#pragma unroll
  for (int j = 0; j < 16; ++j) tile[r][cc + j] = in[(size_t)(r0 + r) * HD + cc + j];
  __syncthreads();
  int c = t >> 2, rr = (t & 3) * 16;
#pragma unroll
  for (int j = 0; j < 16; ++j) o[(size_t)c * DIN + r0 + rr + j] = f2bf(tile[rr + j][c]);
}

// Wo [1024][1024] fp32 -> Wot [1024 n][1024 k] bf16
__global__ __launch_bounds__(256) void wt_kernel(const float* __restrict__ in,
                                                 short* __restrict__ out, int R, int C) {
  __shared__ float tile[64][65];
  int r0 = blockIdx.y * 64, c0 = blockIdx.x * 64;
  int t = threadIdx.x;
  int r = t >> 2, cc = (t & 3) * 16;
#pragma unroll
  for (int j = 0; j < 16; ++j) tile[r][cc + j] = in[(size_t)(r0 + r) * C + c0 + cc + j];
  __syncthreads();
  int c = t >> 2, rr = (t & 3) * 16;
#pragma unroll
  for (int j = 0; j < 16; ++j) out[(size_t)(c0 + c) * R + r0 + rr + j] = f2bf(tile[rr + j][c]);
}

#define QSCL 0.18033688011112042f  // 0.125 * log2(e), folded into q at proj time

// 128x128-tile GEMM: fp32 A reg-staged via cvt_pk, B via global_load_lds.
// q (pre-scaled), k row-major [B,H,S,64]; v transposed [B,H,64,S].
__global__ __launch_bounds__(256) void proj_kernel(
    const float* __restrict__ Q, const float* __restrict__ K, const float* __restrict__ V,
    const short* __restrict__ wt,
    const float* __restrict__ bq, const float* __restrict__ bk, const float* __restrict__ bv,
    short* __restrict__ qb, short* __restrict__ kb, short* __restrict__ vt) {
  int mt = blockIdx.x, nt = blockIdx.y, z = blockIdx.z;
  const float* X = z == 0 ? Q : (z == 1 ? K : V);
  const short* Bt = wt + (size_t)z * (DIN * DIN);
  const float* bias = z == 0 ? bq : (z == 1 ? bk : bv);

  __shared__ __align__(16) short Al[128 * 32];
  __shared__ __align__(16) short Bl[128 * 32];

  int t = threadIdx.x, wid = t >> 6, lane = t & 63;
  int lrow = lane & 15, lhi = lane >> 4;
  int wr = wid >> 1, wc = wid & 1;
  int row0 = mt * 128, col0 = nt * 128;

  int arow = t >> 1, acol = (t & 1) * 16;
  const float* aF = X + (size_t)(row0 + arow) * DIN + acol;
  short* aW = &Al[arow * 32 + acol];

  const short* bG = Bt + (size_t)(col0 + wid * 16 + (lane >> 2)) * DIN + (lane & 3) * 8;
  short* bL0 = &Bl[wid * 512];
  short* bL1 = &Bl[(4 + wid) * 512];

  const short* aR = &Al[(wr * 64 + lrow) * 32 + lhi * 8];
  const short* bR = &Bl[(wc * 64 + lrow) * 32 + lhi * 8];

  f32x4 acc[4][4] = {};
  for (int kk = 0; kk < DIN; kk += 32) {
    gload_lds16(bG + kk, bL0);
    gload_lds16(bG + 64 * DIN + kk, bL1);
    float4 x0 = *(const float4*)(aF + kk);
    float4 x1 = *(const float4*)(aF + kk + 4);
    float4 x2 = *(const float4*)(aF + kk + 8);
    float4 x3 = *(const float4*)(aF + kk + 12);
    u32x4 pA, pB;
    pA[0] = pk2(x0.x, x0.y); pA[1] = pk2(x0.z, x0.w);
    pA[2] = pk2(x1.x, x1.y); pA[3] = pk2(x1.z, x1.w);
    pB[0] = pk2(x2.x, x2.y); pB[1] = pk2(x2.z, x2.w);
    pB[2] = pk2(x3.x, x3.y); pB[3] = pk2(x3.z, x3.w);
    *(u32x4*)aW = pA;
    *(u32x4*)(aW + 8) = pB;
    __syncthreads();
    bf16x8 af[4], bfv[4];
#pragma unroll
    for (int m = 0; m < 4; ++m) af[m] = *(const bf16x8*)(aR + m * 512);
#pragma unroll
    for (int n = 0; n < 4; ++n) bfv[n] = *(const bf16x8*)(bR + n * 512);
#pragma unroll
    for (int m = 0; m < 4; ++m)
#pragma unroll
      for (int n = 0; n < 4; ++n)
        acc[m][n] = __builtin_amdgcn_mfma_f32_16x16x32_bf16(af[m], bfv[n], acc[m][n], 0, 0, 0);
    __syncthreads();
  }
#pragma unroll
  for (int m = 0; m < 4; ++m) {
#pragma unroll
    for (int n = 0; n < 4; ++n) {
      int c = col0 + wc * 64 + n * 16 + lrow;
      int h = c >> 6, hc = c & 63;
      float bval = bias[c];
#pragma unroll
      for (int i = 0; i < 4; ++i) {
        int r = row0 + wr * 64 + m * 16 + lhi * 4 + i;
        int b = r >> 11, s = r & 2047;
        float val = acc[m][n][i] + bval;
        if (z == 0) val *= QSCL;
        if (z == 2) vt[((size_t)(b * NH + h) * HD + hc) * SEQ + s] = f2bf(val);
        else {
          short* o = z == 0 ? qb : kb;
          o[((size_t)(b * NH + h) * SEQ + s) * HD + hc] = f2bf(val);
        }
      }
    }
  }
}

// Flash attention, swapped-operand 32x32x16, in-register softmax.
// 4 waves x 32 q-rows = 128 q/block. KV block 128 = 2x64 subtiles per iteration
// (doubles in-flight ILP across the serial chain). Double-buffered staging.
// permlane32_swap pack-exchange (T12). LDS 64KB -> 2 blocks/CU.
__global__ __launch_bounds__(256) void attn_kernel(
    const short* __restrict__ qb, const short* __restrict__ kb,
    const short* __restrict__ vt, short* __restrict__ ob) {
  int qt = blockIdx.x, h = blockIdx.y, bz = blockIdx.z;
  int t = threadIdx.x, wid = t >> 6, lane = t & 63;
  int l31 = lane & 31, hi = lane >> 5;

  __shared__ __align__(16) short kl[2][2][64 * 64];
  __shared__ __align__(16) short vl[2][2][64 * 64];

  size_t bh = (size_t)(bz * NH + h);
  const short* kbase = kb + bh * (size_t)SEQ * HD;
  const short* vbase = vt + bh * (size_t)HD * SEQ;

  int qg = qt * 128 + wid * 32 + l31;
  const short* qrow = qb + (bh * SEQ + qg) * HD + hi * 8;
  bf16x8 qf0 = *(const bf16x8*)(qrow);
  bf16x8 qf1 = *(const bf16x8*)(qrow + 16);
  bf16x8 qf2 = *(const bf16x8*)(qrow + 32);
  bf16x8 qf3 = *(const bf16x8*)(qrow + 48);

  // staging: wave w rows 16w..16w+15 per subtile; LDS dest linear, source pre-swizzled
  int srow = wid * 16 + (lane >> 3);
  int swc = ((lane & 7) ^ (srow & 7)) * 8;
  const short* kg = kbase + (size_t)srow * HD + swc;
  const short* vg = vbase + (size_t)srow * SEQ + swc;

  f32x16 o0, o1;
#pragma unroll
  for (int i = 0; i < 16; ++i) { o0[i] = 0.f; o1[i] = 0.f; }
  float mrun = -1e30f, lrun = 0.f;

  int ksw = (l31 & 7) << 3;  // read-side swizzle

#define STAGE(T0, B)                                                        \
  do {                                                                      \
    gload_lds16(kg + (size_t)(T0)*HD, &kl[B][0][wid * 1024]);               \
    gload_lds16(kg + (size_t)((T0) + 8) * HD, &kl[B][0][wid * 1024 + 512]); \
    gload_lds16(kg + (size_t)((T0) + 64) * HD, &kl[B][1][wid * 1024]);      \
    gload_lds16(kg + (size_t)((T0) + 72) * HD, &kl[B][1][wid * 1024 + 512]);\
    gload_lds16(vg + (T0), &vl[B][0][wid * 1024]);                          \
    gload_lds16(vg + (T0) + 8 * SEQ, &vl[B][0][wid * 1024 + 512]);          \
    gload_lds16(vg + (T0) + 64, &vl[B][1][wid * 1024]);                     \
    gload_lds16(vg + (T0) + 64 + 8 * SEQ, &vl[B][1][wid * 1024 + 512]);     \
  } while (0)

  STAGE(0, 0);
  __syncthreads();
  int cur = 0;

  for (int t0 = 0; t0 < SEQ; t0 += 128) {
    if (t0 + 128 < SEQ) STAGE(t0 + 128, cur ^ 1);  // issue early, lands during compute

    // QK^T on both subtiles: P^T[kpos][q]
    f32x16 cA0, cA1, cB0, cB1;
#pragma unroll
    for (int i = 0; i < 16; ++i) { cA0[i] = 0.f; cA1[i] = 0.f; cB0[i] = 0.f; cB1[i] = 0.f; }
#pragma unroll
    for (int dk = 0; dk < 4; ++dk) {
      int col = (dk * 16 + hi * 8) ^ ksw;
      bf16x8 qv = dk == 0 ? qf0 : dk == 1 ? qf1 : dk == 2 ? qf2 : qf3;
      bf16x8 kA0 = *(const bf16x8*)&kl[cur][0][l31 * 64 + col];
      bf16x8 kA1 = *(const bf16x8*)&kl[cur][0][(32 + l31) * 64 + col];
      bf16x8 kB0 = *(const bf16x8*)&kl[cur][1][l31 * 64 + col];
      bf16x8 kB1 = *(const bf16x8*)&kl[cur][1][(32 + l31) * 64 + col];
      cA0 = __builtin_amdgcn_mfma_f32_32x32x16_bf16(kA0, qv, cA0, 0, 0, 0);
      cA1 = __builtin_amdgcn_mfma_f32_32x32x16_bf16(kA1, qv, cA1, 0, 0, 0);
      cB0 = __builtin_amdgcn_mfma_f32_32x32x16_bf16(kB0, qv, cB0, 0, 0, 0);
      cB1 = __builtin_amdgcn_mfma_f32_32x32x16_bf16(kB1, qv, cB1, 0, 0, 0);
    }

    // online softmax over 128 kpos, in-register (tree reduce)
    float tm[16];
#pragma unroll
    for (int i = 0; i < 16; ++i) tm[i] = fmaxf(fmaxf(cA0[i], cA1[i]), fmaxf(cB0[i], cB1[i]));
#pragma unroll
    for (int i = 0; i < 8; ++i) tm[i] = fmaxf(tm[i], tm[i + 8]);
#pragma unroll
    for (int i = 0; i < 4; ++i) tm[i] = fmaxf(tm[i], tm[i + 4]);
    float mx = fmaxf(fmaxf(tm[0], tm[1]), fmaxf(tm[2], tm[3]));
    mx = fmaxf(mx, __shfl_xor(mx, 32));
    if (!__all(mx - mrun <= 8.f)) {  // defer-max (T13)
      float mnew = fmaxf(mrun, mx);
      float corr = __builtin_amdgcn_exp2f(mrun - mnew);
      lrun *= corr;
#pragma unroll
      for (int i = 0; i < 16; ++i) { o0[i] *= corr; o1[i] *= corr; }
      mrun = mnew;
    }
#pragma unroll
    for (int i = 0; i < 16; ++i) cA0[i] = __builtin_amdgcn_exp2f(cA0[i] - mrun);
#pragma unroll
    for (int i = 0; i < 16; ++i) cA1[i] = __builtin_amdgcn_exp2f(cA1[i] - mrun);
#pragma unroll
    for (int i = 0; i < 16; ++i) cB0[i] = __builtin_amdgcn_exp2f(cB0[i] - mrun);
#pragma unroll
    for (int i = 0; i < 16; ++i) cB1[i] = __builtin_amdgcn_exp2f(cB1[i] - mrun);
    float ts[16];
#pragma unroll
    for (int i = 0; i < 16; ++i) ts[i] = (cA0[i] + cA1[i]) + (cB0[i] + cB1[i]);
#pragma unroll
    for (int i = 0; i < 8; ++i) ts[i] += ts[i + 8];
#pragma unroll
    for (int i = 0; i < 4; ++i) ts[i] += ts[i + 4];
    float ps = (ts[0] + ts[1]) + (ts[2] + ts[3]);
    ps += __shfl_xor(ps, 32);
    lrun += ps;

    // pack P to bf16 + permlane32_swap exchange -> PV fragments (one swap = 2 words)
    unsigned u0 = pk2(cA0[0], cA0[1]),   u1 = pk2(cA0[2], cA0[3]);
    unsigned u2 = pk2(cA0[4], cA0[5]),   u3 = pk2(cA0[6], cA0[7]);
    unsigned u4 = pk2(cA0[8], cA0[9]),   u5 = pk2(cA0[10], cA0[11]);
    unsigned u6 = pk2(cA0[12], cA0[13]), u7 = pk2(cA0[14], cA0[15]);
    pl32swap(u0, u2); pl32swap(u1, u3); pl32swap(u4, u6); pl32swap(u5, u7);
    bf16x8 fA0 = mkfrag(u0, u1, u2, u3);
    bf16x8 fA1 = mkfrag(u4, u5, u6, u7);
    unsigned v0 = pk2(cA1[0], cA1[1]),   v1 = pk2(cA1[2], cA1[3]);
    unsigned v2 = pk2(cA1[4], cA1[5]),   v3 = pk2(cA1[6], cA1[7]);
    unsigned v4 = pk2(cA1[8], cA1[9]),   v5 = pk2(cA1[10], cA1[11]);
    unsigned v6 = pk2(cA1[12], cA1[13]), v7 = pk2(cA1[14], cA1[15]);
    pl32swap(v0, v2); pl32swap(v1, v3); pl32swap(v4, v6); pl32swap(v5, v7);
    bf16x8 fA2 = mkfrag(v0, v1, v2, v3);
    bf16x8 fA3 = mkfrag(v4, v5, v6, v7);
    unsigned w0 = pk2(cB0[0], cB0[1]),   w1 = pk2(cB0[2], cB0[3]);
    unsigned w2 = pk2(cB0[4], cB0[5]),   w3 = pk2(cB0[6], cB0[7]);
    unsigned w4 = pk2(cB0[8], cB0[9]),   w5 = pk2(cB0[10], cB0[11]);
    unsigned w6 = pk2(cB0[12], cB0[13]), w7 = pk2(cB0[14], cB0[15]);
    pl32swap(w0, w2); pl32swap(w1, w3); pl32swap(w4, w6); pl32swap(w5, w7);
    bf16x8 fB0 = mkfrag(w0, w1, w2, w3);
    bf16x8 fB1 = mkfrag(w4, w5, w6, w7);
    unsigned y0 = pk2(cB1[0], cB1[1]),   y1 = pk2(cB1[2], cB1[3]);
    unsigned y2 = pk2(cB1[4], cB1[5]),   y3 = pk2(cB1[6], cB1[7]);
    unsigned y4 = pk2(cB1[8], cB1[9]),   y5 = pk2(cB1[10], cB1[11]);
    unsigned y6 = pk2(cB1[12], cB1[13]), y7 = pk2(cB1[14], cB1[15]);
    pl32swap(y0, y2); pl32swap(y1, y3); pl32swap(y4, y6); pl32swap(y5, y7);
    bf16x8 fB2 = mkfrag(y0, y1, y2, y3);
    bf16x8 fB3 = mkfrag(y4, y5, y6, y7);

    // PV on both subtiles: O^T[d][q]
#pragma unroll
    for (int kc4 = 0; kc4 < 4; ++kc4) {
      bf16x8 pf = kc4 == 0 ? fA0 : kc4 == 1 ? fA1 : kc4 == 2 ? fA2 : fA3;
      int col = (kc4 * 16 + hi * 8) ^ ksw;
      bf16x8 va = *(const bf16x8*)&vl[cur][0][l31 * 64 + col];
      bf16x8 vb = *(const bf16x8*)&vl[cur][0][(32 + l31) * 64 + col];
      o0 = __builtin_amdgcn_mfma_f32_32x32x16_bf16(va, pf, o0, 0, 0, 0);
      o1 = __builtin_amdgcn_mfma_f32_32x32x16_bf16(vb, pf, o1, 0, 0, 0);
    }
#pragma unroll
    for (int kc4 = 0; kc4 < 4; ++kc4) {
      bf16x8 pf = kc4 == 0 ? fB0 : kc4 == 1 ? fB1 : kc4 == 2 ? fB2 : fB3;
      int col = (kc4 * 16 + hi * 8) ^ ksw;
      bf16x8 va = *(const bf16x8*)&vl[cur][1][l31 * 64 + col];
      bf16x8 vb = *(const bf16x8*)&vl[cur][1][(32 + l31) * 64 + col];
      o0 = __builtin_amdgcn_mfma_f32_32x32x16_bf16(va, pf, o0, 0, 0, 0);
      o1 = __builtin_amdgcn_mfma_f32_32x32x16_bf16(vb, pf, o1, 0, 0, 0);
    }
    __syncthreads();  // drains next-tile stage (overlapped) + protects buffer swap
    cur ^= 1;
  }
#undef STAGE

  float inv = 1.0f / lrun;
  short* orow = ob + ((size_t)(bz * SEQ + qg)) * DIN + h * HD;
#pragma unroll
  for (int r = 0; r < 16; ++r) {
    int d = (r & 3) + 8 * (r >> 2) + 4 * hi;
    orow[d] = f2bf(o0[r] * inv);
    orow[32 + d] = f2bf(o1[r] * inv);
  }
}

// out projection: 64x128-tile GEMM (512 blocks = 2/CU), fp32 out + bias
__global__ __launch_bounds__(256) void oproj_kernel(
    const short* __restrict__ ob, const short* __restrict__ wto,
    const float* __restrict__ bo, float* __restrict__ out) {
  int mt = blockIdx.x, nt = blockIdx.y;
  __shared__ __align__(16) short Al[64 * 32];
  __shared__ __align__(16) short Bl[128 * 32];
  int t = threadIdx.x, wid = t >> 6, lane = t & 63;
  int lrow = lane & 15, lhi = lane >> 4;
  int wr = wid >> 1, wc = wid & 1;
  int row0 = mt * 64, col0 = nt * 128;

  const short* aG = ob + (size_t)(row0 + wid * 16 + (lane >> 2)) * DIN + (lane & 3) * 8;
  const short* bG = wto + (size_t)(col0 + wid * 16 + (lane >> 2)) * DIN + (lane & 3) * 8;
  short* aL = &Al[wid * 512];
  short* bL0 = &Bl[wid * 512];
  short* bL1 = &Bl[(4 + wid) * 512];
  const short* aR = &Al[(wr * 32 + lrow) * 32 + lhi * 8];
  const short* bR = &Bl[(wc * 64 + lrow) * 32 + lhi * 8];

  f32x4 acc[2][4] = {};
  for (int kk = 0; kk < DIN; kk += 32) {
    gload_lds16(aG + kk, aL);
    gload_lds16(bG + kk, bL0);
    gload_lds16(bG + 64 * DIN + kk, bL1);
    __syncthreads();
    bf16x8 af[2], bfv[4];
#pragma unroll
    for (int m = 0; m < 2; ++m) af[m] = *(const bf16x8*)(aR + m * 512);
#pragma unroll
    for (int n = 0; n < 4; ++n) bfv[n] = *(const bf16x8*)(bR + n * 512);
#pragma unroll
    for (int m = 0; m < 2; ++m)
#pragma unroll
      for (int n = 0; n < 4; ++n)
        acc[m][n] = __builtin_amdgcn_mfma_f32_16x16x32_bf16(af[m], bfv[n], acc[m][n], 0, 0, 0);
    __syncthreads();
  }
#pragma unroll
  for (int m = 0; m < 2; ++m) {
#pragma unroll
    for (int n = 0; n < 4; ++n) {
      int c = col0 + wc * 64 + n * 16 + lrow;
      float bval = bo[c];
#pragma unroll
      for (int i = 0; i < 4; ++i) {
        int r = row0 + wr * 32 + m * 16 + lhi * 4 + i;
        out[(size_t)r * DIN + c] = acc[m][n][i] + bval;
      }
    }
  }
}

extern "C" void kernel_launch(void* const* d_in, const int* in_sizes, int n_in,
                              void* d_out, int out_size, void* d_ws, size_t ws_size,
                              hipStream_t stream) {
  const float* Q  = (const float*)d_in[0];
  const float* K  = (const float*)d_in[1];
  const float* V  = (const float*)d_in[2];
  const float* Wq = (const float*)d_in[3];
  const float* bq = (const float*)d_in[4];
  const float* Wk = (const float*)d_in[5];
  const float* bk = (const float*)d_in[6];
  const float* Wv = (const float*)d_in[7];
  const float* bv = (const float*)d_in[8];
  const float* Wo = (const float*)d_in[9];
  const float* bo = (const float*)d_in[10];
  float* out = (float*)d_out;

  short* ws = (short*)d_ws;
  const size_t NX = (size_t)NB * SEQ * DIN;        // 4194304 elems (8 MiB bf16)
  const size_t NW = (size_t)NH * HD * DIN;         // 1048576
  // 40 MiB fixed layout (R1/R3-proven)
  short* qbuf = ws;
  short* kbuf = qbuf + NX;
  short* vtb  = kbuf + NX;
  short* obuf = vtb + NX;
  short* wtq  = obuf + NX;   // [3][H][64][1024] combined
  short* wto  = wtq + 3 * NW;

  wt3_kernel<<<dim3(1, 16, 48), 256, 0, stream>>>(Wq, Wk, Wv, wtq);
  wt_kernel<<<dim3(16, 16, 1), 256, 0, stream>>>(Wo, wto, DIN, DIN);
  proj_kernel<<<dim3(32, 8, 3), 256, 0, stream>>>(Q, K, V, wtq, bq, bk, bv,
                                                  qbuf, kbuf, vtb);
  attn_kernel<<<dim3(16, 16, 2), 256, 0, stream>>>(qbuf, kbuf, vtb, obuf);
  oproj_kernel<<<dim3(64, 8), 256, 0, stream>>>(obuf, wto, bo, out);
}

// Round 11
// 249.943 us; speedup vs baseline: 1.0182x; 1.0182x over previous
//
#include <hip/hip_runtime.h>
#include <hip/hip_bf16.h>

#define DIN 1024
#define NH 16
#define HD 64
#define SEQ 2048
#define NB 2

typedef __attribute__((ext_vector_type(8))) short bf16x8;
typedef __attribute__((ext_vector_type(4))) float f32x4;
typedef __attribute__((ext_vector_type(16))) float f32x16;
typedef __attribute__((ext_vector_type(4))) unsigned u32x4;

__device__ inline short f2bf(float f) {
  union { float f; unsigned u; } v; v.f = f;
  unsigned r = v.u + 0x7fff + ((v.u >> 16) & 1);
  return (short)(r >> 16);
}

// 2x f32 -> packed bf16 pair (lo, hi) in one instruction (T12 recipe)
__device__ inline unsigned pk2(float lo, float hi) {
  unsigned r;
  asm("v_cvt_pk_bf16_f32 %0, %1, %2" : "=v"(r) : "v"(lo), "v"(hi));
  return r;
}

// swap a.hi32lanes <-> b.lo32lanes in-place (both outputs usable)
__device__ inline void pl32swap(unsigned& a, unsigned& b) {
  asm("v_permlane32_swap_b32 %0, %1" : "+v"(a), "+v"(b));
}

union U8 { unsigned u[4]; bf16x8 v; };
__device__ inline bf16x8 mkfrag(unsigned a, unsigned b, unsigned c, unsigned d) {
  U8 x; x.u[0] = a; x.u[1] = b; x.u[2] = c; x.u[3] = d; return x.v;
}

__device__ __forceinline__ void gload_lds16(const void* g, void* l) {
  __builtin_amdgcn_global_load_lds(
      (const __attribute__((address_space(1))) unsigned*)g,
      (__attribute__((address_space(3))) unsigned*)l, 16, 0, 0);
}

// Wq/Wk/Wv [H][1024][64] fp32 -> Wt [3][H][64][1024] bf16 (transposed per head)
__global__ __launch_bounds__(256) void wt3_kernel(
    const float* __restrict__ Wq, const float* __restrict__ Wk, const float* __restrict__ Wv,
    short* __restrict__ out) {
  int zz = blockIdx.z; int which = zz >> 4, h = zz & 15;
  const float* in = (which == 0 ? Wq : (which == 1 ? Wk : Wv)) + (size_t)h * (DIN * HD);
  short* o = out + (size_t)which * (NH * HD * DIN) + (size_t)h * (HD * DIN);
  __shared__ float tile[64][65];
  int r0 = blockIdx.y * 64;
  int t = threadIdx.x;
  int r = t >> 2, cc = (t & 3) * 16;
#pragma unroll
  for (int j = 0; j < 16; ++j) tile[r][cc + j] = in[(size_t)(r0 + r) * HD + cc + j];
  __syncthreads();
  int c = t >> 2, rr = (t & 3) * 16;
#pragma unroll
  for (int j = 0; j < 16; ++j) o[(size_t)c * DIN + r0 + rr + j] = f2bf(tile[rr + j][c]);
}

// Wo [1024][1024] fp32 -> Wot [1024 n][1024 k] bf16
__global__ __launch_bounds__(256) void wt_kernel(const float* __restrict__ in,
                                                 short* __restrict__ out, int R, int C) {
  __shared__ float tile[64][65];
  int r0 = blockIdx.y * 64, c0 = blockIdx.x * 64;
  int t = threadIdx.x;
  int r = t >> 2, cc = (t & 3) * 16;
#pragma unroll
  for (int j = 0; j < 16; ++j) tile[r][cc + j] = in[(size_t)(r0 + r) * C + c0 + cc + j];
  __syncthreads();
  int c = t >> 2, rr = (t & 3) * 16;
#pragma unroll
  for (int j = 0; j < 16; ++j) out[(size_t)(c0 + c) * R + r0 + rr + j] = f2bf(tile[rr + j][c]);
}

#define QSCL 0.18033688011112042f  // 0.125 * log2(e), folded into q at proj time

// 128x128-tile GEMM, double-buffered LDS, 1 barrier/iter (stage-early T14):
// fp32 A reg-staged via cvt_pk, B via global_load_lds.
// q (pre-scaled), k row-major [B,H,S,64]; v transposed [B,H,64,S].
__global__ __launch_bounds__(256) void proj_kernel(
    const float* __restrict__ Q, const float* __restrict__ K, const float* __restrict__ V,
    const short* __restrict__ wt,
    const float* __restrict__ bq, const float* __restrict__ bk, const float* __restrict__ bv,
    short* __restrict__ qb, short* __restrict__ kb, short* __restrict__ vt) {
  int mt = blockIdx.x, nt = blockIdx.y, z = blockIdx.z;
  const float* X = z == 0 ? Q : (z == 1 ? K : V);
  const short* Bt = wt + (size_t)z * (DIN * DIN);
  const float* bias = z == 0 ? bq : (z == 1 ? bk : bv);

  __shared__ __align__(16) short Al[2][128 * 32];
  __shared__ __align__(16) short Bl[2][128 * 32];

  int t = threadIdx.x, wid = t >> 6, lane = t & 63;
  int lrow = lane & 15, lhi = lane >> 4;
  int wr = wid >> 1, wc = wid & 1;
  int row0 = mt * 128, col0 = nt * 128;

  int arow = t >> 1, acol = (t & 1) * 16;
  const float* aF = X + (size_t)(row0 + arow) * DIN + acol;
  int aOff = arow * 32 + acol;

  const short* bG = Bt + (size_t)(col0 + wid * 16 + (lane >> 2)) * DIN + (lane & 3) * 8;

  f32x4 acc[4][4] = {};

  // prologue: stage k=0 into buffer 0
  {
    gload_lds16(bG, &Bl[0][wid * 512]);
    gload_lds16(bG + 64 * DIN, &Bl[0][(4 + wid) * 512]);
    float4 x0 = *(const float4*)(aF);
    float4 x1 = *(const float4*)(aF + 4);
    float4 x2 = *(const float4*)(aF + 8);
    float4 x3 = *(const float4*)(aF + 12);
    u32x4 pA, pB;
    pA[0] = pk2(x0.x, x0.y); pA[1] = pk2(x0.z, x0.w);
    pA[2] = pk2(x1.x, x1.y); pA[3] = pk2(x1.z, x1.w);
    pB[0] = pk2(x2.x, x2.y); pB[1] = pk2(x2.z, x2.w);
    pB[2] = pk2(x3.x, x3.y); pB[3] = pk2(x3.z, x3.w);
    *(u32x4*)&Al[0][aOff] = pA;
    *(u32x4*)&Al[0][aOff + 8] = pB;
  }
  __syncthreads();

  for (int kk = 0; kk < DIN; kk += 32) {
    int cur = (kk >> 5) & 1;
    bool more = (kk + 32) < DIN;
    float4 x0, x1, x2, x3;
    if (more) {  // issue next-iter loads early: DMA + A-loads land during MFMA
      gload_lds16(bG + kk + 32, &Bl[cur ^ 1][wid * 512]);
      gload_lds16(bG + 64 * DIN + kk + 32, &Bl[cur ^ 1][(4 + wid) * 512]);
      x0 = *(const float4*)(aF + kk + 32);
      x1 = *(const float4*)(aF + kk + 36);
      x2 = *(const float4*)(aF + kk + 40);
      x3 = *(const float4*)(aF + kk + 44);
    }
    const short* aR = &Al[cur][(wr * 64 + lrow) * 32 + lhi * 8];
    const short* bR = &Bl[cur][(wc * 64 + lrow) * 32 + lhi * 8];
    bf16x8 af[4], bfv[4];
#pragma unroll
    for (int m = 0; m < 4; ++m) af[m] = *(const bf16x8*)(aR + m * 512);
#pragma unroll
    for (int n = 0; n < 4; ++n) bfv[n] = *(const bf16x8*)(bR + n * 512);
#pragma unroll
    for (int m = 0; m < 4; ++m)
#pragma unroll
      for (int n = 0; n < 4; ++n)
        acc[m][n] = __builtin_amdgcn_mfma_f32_16x16x32_bf16(af[m], bfv[n], acc[m][n], 0, 0, 0);
    if (more) {  // convert + write A for next iter into the other buffer
      u32x4 pA, pB;
      pA[0] = pk2(x0.x, x0.y); pA[1] = pk2(x0.z, x0.w);
      pA[2] = pk2(x1.x, x1.y); pA[3] = pk2(x1.z, x1.w);
      pB[0] = pk2(x2.x, x2.y); pB[1] = pk2(x2.z, x2.w);
      pB[2] = pk2(x3.x, x3.y); pB[3] = pk2(x3.z, x3.w);
      *(u32x4*)&Al[cur ^ 1][aOff] = pA;
      *(u32x4*)&Al[cur ^ 1][aOff + 8] = pB;
    }
    __syncthreads();  // one barrier/iter: next buffer ready, current reads done
  }

#pragma unroll
  for (int m = 0; m < 4; ++m) {
#pragma unroll
    for (int n = 0; n < 4; ++n) {
      int c = col0 + wc * 64 + n * 16 + lrow;
      int h = c >> 6, hc = c & 63;
      float bval = bias[c];
#pragma unroll
      for (int i = 0; i < 4; ++i) {
        int r = row0 + wr * 64 + m * 16 + lhi * 4 + i;
        int b = r >> 11, s = r & 2047;
        float val = acc[m][n][i] + bval;
        if (z == 0) val *= QSCL;
        if (z == 2) vt[((size_t)(b * NH + h) * HD + hc) * SEQ + s] = f2bf(val);
        else {
          short* o = z == 0 ? qb : kb;
          o[((size_t)(b * NH + h) * SEQ + s) * HD + hc] = f2bf(val);
        }
      }
    }
  }
}

// Flash attention, swapped-operand 32x32x16, in-register softmax.
// 4 waves x 32 q-rows = 128 q/block. KV block 128 = 2x64 subtiles per iteration.
// Double-buffered staging, permlane32_swap pack-exchange (T12). LDS 64KB.
__global__ __launch_bounds__(256) void attn_kernel(
    const short* __restrict__ qb, const short* __restrict__ kb,
    const short* __restrict__ vt, short* __restrict__ ob) {
  int qt = blockIdx.x, h = blockIdx.y, bz = blockIdx.z;
  int t = threadIdx.x, wid = t >> 6, lane = t & 63;
  int l31 = lane & 31, hi = lane >> 5;

  __shared__ __align__(16) short kl[2][2][64 * 64];
  __shared__ __align__(16) short vl[2][2][64 * 64];

  size_t bh = (size_t)(bz * NH + h);
  const short* kbase = kb + bh * (size_t)SEQ * HD;
  const short* vbase = vt + bh * (size_t)HD * SEQ;

  int qg = qt * 128 + wid * 32 + l31;
  const short* qrow = qb + (bh * SEQ + qg) * HD + hi * 8;
  bf16x8 qf0 = *(const bf16x8*)(qrow);
  bf16x8 qf1 = *(const bf16x8*)(qrow + 16);
  bf16x8 qf2 = *(const bf16x8*)(qrow + 32);
  bf16x8 qf3 = *(const bf16x8*)(qrow + 48);

  // staging: wave w rows 16w..16w+15 per subtile; LDS dest linear, source pre-swizzled
  int srow = wid * 16 + (lane >> 3);
  int swc = ((lane & 7) ^ (srow & 7)) * 8;
  const short* kg = kbase + (size_t)srow * HD + swc;
  const short* vg = vbase + (size_t)srow * SEQ + swc;

  f32x16 o0, o1;
#pragma unroll
  for (int i = 0; i < 16; ++i) { o0[i] = 0.f; o1[i] = 0.f; }
  float mrun = -1e30f, lrun = 0.f;

  int ksw = (l31 & 7) << 3;  // read-side swizzle

#define STAGE(T0, B)                                                        \
  do {                                                                      \
    gload_lds16(kg + (size_t)(T0)*HD, &kl[B][0][wid * 1024]);               \
    gload_lds16(kg + (size_t)((T0) + 8) * HD, &kl[B][0][wid * 1024 + 512]); \
    gload_lds16(kg + (size_t)((T0) + 64) * HD, &kl[B][1][wid * 1024]);      \
    gload_lds16(kg + (size_t)((T0) + 72) * HD, &kl[B][1][wid * 1024 + 512]);\
    gload_lds16(vg + (T0), &vl[B][0][wid * 1024]);                          \
    gload_lds16(vg + (T0) + 8 * SEQ, &vl[B][0][wid * 1024 + 512]);          \
    gload_lds16(vg + (T0) + 64, &vl[B][1][wid * 1024]);                     \
    gload_lds16(vg + (T0) + 64 + 8 * SEQ, &vl[B][1][wid * 1024 + 512]);     \
  } while (0)

  STAGE(0, 0);
  __syncthreads();
  int cur = 0;

  for (int t0 = 0; t0 < SEQ; t0 += 128) {
    if (t0 + 128 < SEQ) STAGE(t0 + 128, cur ^ 1);  // issue early, lands during compute

    // QK^T on both subtiles: P^T[kpos][q]
    f32x16 cA0, cA1, cB0, cB1;
#pragma unroll
    for (int i = 0; i < 16; ++i) { cA0[i] = 0.f; cA1[i] = 0.f; cB0[i] = 0.f; cB1[i] = 0.f; }
#pragma unroll
    for (int dk = 0; dk < 4; ++dk) {
      int col = (dk * 16 + hi * 8) ^ ksw;
      bf16x8 qv = dk == 0 ? qf0 : dk == 1 ? qf1 : dk == 2 ? qf2 : qf3;
      bf16x8 kA0 = *(const bf16x8*)&kl[cur][0][l31 * 64 + col];
      bf16x8 kA1 = *(const bf16x8*)&kl[cur][0][(32 + l31) * 64 + col];
      bf16x8 kB0 = *(const bf16x8*)&kl[cur][1][l31 * 64 + col];
      bf16x8 kB1 = *(const bf16x8*)&kl[cur][1][(32 + l31) * 64 + col];
      cA0 = __builtin_amdgcn_mfma_f32_32x32x16_bf16(kA0, qv, cA0, 0, 0, 0);
      cA1 = __builtin_amdgcn_mfma_f32_32x32x16_bf16(kA1, qv, cA1, 0, 0, 0);
      cB0 = __builtin_amdgcn_mfma_f32_32x32x16_bf16(kB0, qv, cB0, 0, 0, 0);
      cB1 = __builtin_amdgcn_mfma_f32_32x32x16_bf16(kB1, qv, cB1, 0, 0, 0);
    }

    // online softmax over 128 kpos, in-register (tree reduce)
    float tm[16];
#pragma unroll
    for (int i = 0; i < 16; ++i) tm[i] = fmaxf(fmaxf(cA0[i], cA1[i]), fmaxf(cB0[i], cB1[i]));
#pragma unroll
    for (int i = 0; i < 8; ++i) tm[i] = fmaxf(tm[i], tm[i + 8]);
#pragma unroll
    for (int i = 0; i < 4; ++i) tm[i] = fmaxf(tm[i], tm[i + 4]);
    float mx = fmaxf(fmaxf(tm[0], tm[1]), fmaxf(tm[2], tm[3]));
    mx = fmaxf(mx, __shfl_xor(mx, 32));
    if (!__all(mx - mrun <= 8.f)) {  // defer-max (T13)
      float mnew = fmaxf(mrun, mx);
      float corr = __builtin_amdgcn_exp2f(mrun - mnew);
      lrun *= corr;
#pragma unroll
      for (int i = 0; i < 16; ++i) { o0[i] *= corr; o1[i] *= corr; }
      mrun = mnew;
    }
#pragma unroll
    for (int i = 0; i < 16; ++i) cA0[i] = __builtin_amdgcn_exp2f(cA0[i] - mrun);
#pragma unroll
    for (int i = 0; i < 16; ++i) cA1[i] = __builtin_amdgcn_exp2f(cA1[i] - mrun);
#pragma unroll
    for (int i = 0; i < 16; ++i) cB0[i] = __builtin_amdgcn_exp2f(cB0[i] - mrun);
#pragma unroll
    for (int i = 0; i < 16; ++i) cB1[i] = __builtin_amdgcn_exp2f(cB1[i] - mrun);
    float ts[16];
#pragma unroll
    for (int i = 0; i < 16; ++i) ts[i] = (cA0[i] + cA1[i]) + (cB0[i] + cB1[i]);
#pragma unroll
    for (int i = 0; i < 8; ++i) ts[i] += ts[i + 8];
#pragma unroll
    for (int i = 0; i < 4; ++i) ts[i] += ts[i + 4];
    float ps = (ts[0] + ts[1]) + (ts[2] + ts[3]);
    ps += __shfl_xor(ps, 32);
    lrun += ps;

    // pack P to bf16 + permlane32_swap exchange -> PV fragments (one swap = 2 words)
    unsigned u0 = pk2(cA0[0], cA0[1]),   u1 = pk2(cA0[2], cA0[3]);
    unsigned u2 = pk2(cA0[4], cA0[5]),   u3 = pk2(cA0[6], cA0[7]);
    unsigned u4 = pk2(cA0[8], cA0[9]),   u5 = pk2(cA0[10], cA0[11]);
    unsigned u6 = pk2(cA0[12], cA0[13]), u7 = pk2(cA0[14], cA0[15]);
    pl32swap(u0, u2); pl32swap(u1, u3); pl32swap(u4, u6); pl32swap(u5, u7);
    bf16x8 fA0 = mkfrag(u0, u1, u2, u3);
    bf16x8 fA1 = mkfrag(u4, u5, u6, u7);
    unsigned v0 = pk2(cA1[0], cA1[1]),   v1 = pk2(cA1[2], cA1[3]);
    unsigned v2 = pk2(cA1[4], cA1[5]),   v3 = pk2(cA1[6], cA1[7]);
    unsigned v4 = pk2(cA1[8], cA1[9]),   v5 = pk2(cA1[10], cA1[11]);
    unsigned v6 = pk2(cA1[12], cA1[13]), v7 = pk2(cA1[14], cA1[15]);
    pl32swap(v0, v2); pl32swap(v1, v3); pl32swap(v4, v6); pl32swap(v5, v7);
    bf16x8 fA2 = mkfrag(v0, v1, v2, v3);
    bf16x8 fA3 = mkfrag(v4, v5, v6, v7);
    unsigned w0 = pk2(cB0[0], cB0[1]),   w1 = pk2(cB0[2], cB0[3]);
    unsigned w2 = pk2(cB0[4], cB0[5]),   w3 = pk2(cB0[6], cB0[7]);
    unsigned w4 = pk2(cB0[8], cB0[9]),   w5 = pk2(cB0[10], cB0[11]);
    unsigned w6 = pk2(cB0[12], cB0[13]), w7 = pk2(cB0[14], cB0[15]);
    pl32swap(w0, w2); pl32swap(w1, w3); pl32swap(w4, w6); pl32swap(w5, w7);
    bf16x8 fB0 = mkfrag(w0, w1, w2, w3);
    bf16x8 fB1 = mkfrag(w4, w5, w6, w7);
    unsigned y0 = pk2(cB1[0], cB1[1]),   y1 = pk2(cB1[2], cB1[3]);
    unsigned y2 = pk2(cB1[4], cB1[5]),   y3 = pk2(cB1[6], cB1[7]);
    unsigned y4 = pk2(cB1[8], cB1[9]),   y5 = pk2(cB1[10], cB1[11]);
    unsigned y6 = pk2(cB1[12], cB1[13]), y7 = pk2(cB1[14], cB1[15]);
    pl32swap(y0, y2); pl32swap(y1, y3); pl32swap(y4, y6); pl32swap(y5, y7);
    bf16x8 fB2 = mkfrag(y0, y1, y2, y3);
    bf16x8 fB3 = mkfrag(y4, y5, y6, y7);

    // PV on both subtiles: O^T[d][q]
#pragma unroll
    for (int kc4 = 0; kc4 < 4; ++kc4) {
      bf16x8 pf = kc4 == 0 ? fA0 : kc4 == 1 ? fA1 : kc4 == 2 ? fA2 : fA3;
      int col = (kc4 * 16 + hi * 8) ^ ksw;
      bf16x8 va = *(const bf16x8*)&vl[cur][0][l31 * 64 + col];
      bf16x8 vb = *(const bf16x8*)&vl[cur][0][(32 + l31) * 64 + col];
      o0 = __builtin_amdgcn_mfma_f32_32x32x16_bf16(va, pf, o0, 0, 0, 0);
      o1 = __builtin_amdgcn_mfma_f32_32x32x16_bf16(vb, pf, o1, 0, 0, 0);
    }
#pragma unroll
    for (int kc4 = 0; kc4 < 4; ++kc4) {
      bf16x8 pf = kc4 == 0 ? fB0 : kc4 == 1 ? fB1 : kc4 == 2 ? fB2 : fB3;
      int col = (kc4 * 16 + hi * 8) ^ ksw;
      bf16x8 va = *(const bf16x8*)&vl[cur][1][l31 * 64 + col];
      bf16x8 vb = *(const bf16x8*)&vl[cur][1][(32 + l31) * 64 + col];
      o0 = __builtin_amdgcn_mfma_f32_32x32x16_bf16(va, pf, o0, 0, 0, 0);
      o1 = __builtin_amdgcn_mfma_f32_32x32x16_bf16(vb, pf, o1, 0, 0, 0);
    }
    __syncthreads();  // drains next-tile stage (overlapped) + protects buffer swap
    cur ^= 1;
  }
#undef STAGE

  float inv = 1.0f / lrun;
  short* orow = ob + ((size_t)(bz * SEQ + qg)) * DIN + h * HD;
#pragma unroll
  for (int r = 0; r < 16; ++r) {
    int d = (r & 3) + 8 * (r >> 2) + 4 * hi;
    orow[d] = f2bf(o0[r] * inv);
    orow[32 + d] = f2bf(o1[r] * inv);
  }
}

// out projection: 64x128-tile GEMM, double-buffered LDS, 1 barrier/iter.
__global__ __launch_bounds__(256) void oproj_kernel(
    const short* __restrict__ ob, const short* __restrict__ wto,
    const float* __restrict__ bo, float* __restrict__ out) {
  int mt = blockIdx.x, nt = blockIdx.y;
  __shared__ __align__(16) short Al[2][64 * 32];
  __shared__ __align__(16) short Bl[2][128 * 32];
  int t = threadIdx.x, wid = t >> 6, lane = t & 63;
  int lrow = lane & 15, lhi = lane >> 4;
  int wr = wid >> 1, wc = wid & 1;
  int row0 = mt * 64, col0 = nt * 128;

  const short* aG = ob + (size_t)(row0 + wid * 16 + (lane >> 2)) * DIN + (lane & 3) * 8;
  const short* bG = wto + (size_t)(col0 + wid * 16 + (lane >> 2)) * DIN + (lane & 3) * 8;

  f32x4 acc[2][4] = {};

  // prologue: stage k=0 into buffer 0
  gload_lds16(aG, &Al[0][wid * 512]);
  gload_lds16(bG, &Bl[0][wid * 512]);
  gload_lds16(bG + 64 * DIN, &Bl[0][(4 + wid) * 512]);
  __syncthreads();

  for (int kk = 0; kk < DIN; kk += 32) {
    int cur = (kk >> 5) & 1;
    if (kk + 32 < DIN) {  // stage next iter early; lands during MFMA
      gload_lds16(aG + kk + 32, &Al[cur ^ 1][wid * 512]);
      gload_lds16(bG + kk + 32, &Bl[cur ^ 1][wid * 512]);
      gload_lds16(bG + 64 * DIN + kk + 32, &Bl[cur ^ 1][(4 + wid) * 512]);
    }
    const short* aR = &Al[cur][(wr * 32 + lrow) * 32 + lhi * 8];
    const short* bR = &Bl[cur][(wc * 64 + lrow) * 32 + lhi * 8];
    bf16x8 af[2], bfv[4];
#pragma unroll
    for (int m = 0; m < 2; ++m) af[m] = *(const bf16x8*)(aR + m * 512);
#pragma unroll
    for (int n = 0; n < 4; ++n) bfv[n] = *(const bf16x8*)(bR + n * 512);
#pragma unroll
    for (int m = 0; m < 2; ++m)
#pragma unroll
      for (int n = 0; n < 4; ++n)
        acc[m][n] = __builtin_amdgcn_mfma_f32_16x16x32_bf16(af[m], bfv[n], acc[m][n], 0, 0, 0);
    __syncthreads();
  }
#pragma unroll
  for (int m = 0; m < 2; ++m) {
#pragma unroll
    for (int n = 0; n < 4; ++n) {
      int c = col0 + wc * 64 + n * 16 + lrow;
      float bval = bo[c];
#pragma unroll
      for (int i = 0; i < 4; ++i) {
        int r = row0 + wr * 32 + m * 16 + lhi * 4 + i;
        out[(size_t)r * DIN + c] = acc[m][n][i] + bval;
      }
    }
  }
}

extern "C" void kernel_launch(void* const* d_in, const int* in_sizes, int n_in,
                              void* d_out, int out_size, void* d_ws, size_t ws_size,
                              hipStream_t stream) {
  const float* Q  = (const float*)d_in[0];
  const float* K  = (const float*)d_in[1];
  const float* V  = (const float*)d_in[2];
  const float* Wq = (const float*)d_in[3];
  const float* bq = (const float*)d_in[4];
  const float* Wk = (const float*)d_in[5];
  const float* bk = (const float*)d_in[6];
  const float* Wv = (const float*)d_in[7];
  const float* bv = (const float*)d_in[8];
  const float* Wo = (const float*)d_in[9];
  const float* bo = (const float*)d_in[10];
  float* out = (float*)d_out;

  short* ws = (short*)d_ws;
  const size_t NX = (size_t)NB * SEQ * DIN;        // 4194304 elems (8 MiB bf16)
  const size_t NW = (size_t)NH * HD * DIN;         // 1048576
  // 40 MiB fixed layout (R1/R3-proven)
  short* qbuf = ws;
  short* kbuf = qbuf + NX;
  short* vtb  = kbuf + NX;
  short* obuf = vtb + NX;
  short* wtq  = obuf + NX;   // [3][H][64][1024] combined
  short* wto  = wtq + 3 * NW;

  wt3_kernel<<<dim3(1, 16, 48), 256, 0, stream>>>(Wq, Wk, Wv, wtq);
  wt_kernel<<<dim3(16, 16, 1), 256, 0, stream>>>(Wo, wto, DIN, DIN);
  proj_kernel<<<dim3(32, 8, 3), 256, 0, stream>>>(Q, K, V, wtq, bq, bk, bv,
                                                  qbuf, kbuf, vtb);
  attn_kernel<<<dim3(16, 16, 2), 256, 0, stream>>>(qbuf, kbuf, vtb, obuf);
  oproj_kernel<<<dim3(64, 8), 256, 0, stream>>>(obuf, wto, bo, out);
}